// Round 1
// baseline (936.920 us; speedup 1.0000x reference)
//
#include <hip/hip_runtime.h>
#include <hip/hip_bf16.h>

typedef __attribute__((ext_vector_type(8))) short bf16x8;
typedef __attribute__((ext_vector_type(4))) float f32x4;
typedef __attribute__((ext_vector_type(8))) unsigned short u16x8;

static __device__ __forceinline__ unsigned short f2bf(float f) {
  unsigned int u = __builtin_bit_cast(unsigned int, f);
  u += 0x7fffu + ((u >> 16) & 1u);
  return (unsigned short)(u >> 16);
}
static __device__ __forceinline__ unsigned int pk2(float lo, float hi) {
  return (unsigned int)f2bf(lo) | ((unsigned int)f2bf(hi) << 16);
}
static __device__ __forceinline__ void gload_lds16(const void* g, void* l) {
  __builtin_amdgcn_global_load_lds(
      (__attribute__((address_space(1))) void*)(g),
      (__attribute__((address_space(3))) void*)(l), 16, 0, 0);
}

// ---------- transpose 1024x1024 f32 (K x N) -> bf16 (N x K) ----------
__global__ __launch_bounds__(256) void transpose_w(const float* __restrict__ W,
                                                   unsigned short* __restrict__ WT) {
  __shared__ float tile[64][65];
  const int bx = blockIdx.x;  // n tile
  const int by = blockIdx.y;  // k tile
  const int t = threadIdx.x;
  const int rr = t >> 6;  // 0..3
  const int cc = t & 63;
#pragma unroll
  for (int i = 0; i < 16; ++i) {
    int r = i * 4 + rr;
    tile[r][cc] = W[(size_t)(by * 64 + r) * 1024 + bx * 64 + cc];
  }
  __syncthreads();
#pragma unroll
  for (int i = 0; i < 16; ++i) {
    int n = i * 4 + rr;
    WT[(size_t)(bx * 64 + n) * 1024 + by * 64 + cc] = f2bf(tile[cc][n]);
  }
}

// ---------- LayerNorm of h[b, t+63] -> x[b, t], pad rows t>=1985 zero ----------
__global__ __launch_bounds__(256) void ln_kernel(const float* __restrict__ H,
                                                 const float* __restrict__ gamma,
                                                 const float* __restrict__ beta,
                                                 float* __restrict__ X) {
  const int row = blockIdx.x;  // 0..16383
  const int b = row >> 11;
  const int t = row & 2047;
  const int tid = threadIdx.x;
  float4* xo = (float4*)(X + (size_t)row * 1024);
  if (t >= 1985) {
    xo[tid] = make_float4(0.f, 0.f, 0.f, 0.f);
    return;
  }
  const float4* hp = (const float4*)(H + (size_t)(b * 2048 + t + 63) * 1024);
  float4 v = hp[tid];
  float s = v.x + v.y + v.z + v.w;
  float q = v.x * v.x + v.y * v.y + v.z * v.z + v.w * v.w;
#pragma unroll
  for (int off = 32; off > 0; off >>= 1) {
    s += __shfl_down(s, off);
    q += __shfl_down(q, off);
  }
  __shared__ float red[8];
  const int lane = tid & 63, wid = tid >> 6;
  if (lane == 0) {
    red[wid] = s;
    red[4 + wid] = q;
  }
  __syncthreads();
  s = red[0] + red[1] + red[2] + red[3];
  q = red[4] + red[5] + red[6] + red[7];
  const float mu = s * (1.0f / 1024.0f);
  const float var = q * (1.0f / 1024.0f) - mu * mu;
  const float rs = rsqrtf(var + 1e-5f);
  const float4 g = ((const float4*)gamma)[tid];
  const float4 bb = ((const float4*)beta)[tid];
  float4 o;
  o.x = (v.x - mu) * rs * g.x + bb.x;
  o.y = (v.y - mu) * rs * g.y + bb.y;
  o.z = (v.z - mu) * rs * g.z + bb.z;
  o.w = (v.w - mu) * rs * g.w + bb.w;
  xo[tid] = o;
}

// ---------- GEMM: C[M x N] = A[M x 1024](f32) @ BT[N x 1024](bf16)^T + bias ----------
// MODE 0: write bf16 to C1 (col<1024) / C2 (col>=1024)
// MODE 1: OUT[(row+63)*1024+col] += acc + bias1[col], only for (row&2047)<1985
template <int MODE>
__global__ __launch_bounds__(256) void gemm128(
    const float* __restrict__ A, const unsigned short* __restrict__ BT,
    const float* __restrict__ bias1, const float* __restrict__ bias2,
    unsigned short* __restrict__ C1, unsigned short* __restrict__ C2,
    float* __restrict__ OUT) {
  __shared__ unsigned short As[128 * 64];
  __shared__ unsigned short Bs[128 * 64];
  const int tid = threadIdx.x;
  const int lane = tid & 63;
  const int wid = tid >> 6;
  const int m0 = blockIdx.y * 128;
  const int n0 = blockIdx.x * 128;
  const int wr = wid >> 1, wc = wid & 1;
  const int lrow = lane & 15;
  const int lk = lane >> 4;

  f32x4 acc[4][4] = {};

  const int sar = tid >> 3;  // 0..31
  const int sac = tid & 7;   // logical k-chunk
  const int brl = lane >> 3; // 0..7
  const int bcl = lane & 7;

  for (int k0 = 0; k0 < 1024; k0 += 64) {
    __syncthreads();
    // B tile: global_load_lds, pre-swizzled source so linear LDS == swizzled layout
#pragma unroll
    for (int is = 0; is < 4; ++is) {
      const int brow = is * 32 + wid * 8 + brl;  // LDS-local row (== n - n0)
      const int bchunk = bcl ^ (brow & 7);
      gload_lds16(BT + (size_t)(n0 + brow) * 1024 + k0 + bchunk * 8,
                  (char*)Bs + (is * 32 + wid * 8) * 128);
    }
    // A tile: f32 -> bf16 register staging, swizzled ds_write_b128
#pragma unroll
    for (int is = 0; is < 4; ++is) {
      const int arow = is * 32 + sar;
      const float4* src = (const float4*)(A + (size_t)(m0 + arow) * 1024 + k0 + sac * 8);
      float4 f0 = src[0];
      float4 f1 = src[1];
      uint4 w;
      w.x = pk2(f0.x, f0.y);
      w.y = pk2(f0.z, f0.w);
      w.z = pk2(f1.x, f1.y);
      w.w = pk2(f1.z, f1.w);
      *(uint4*)((char*)As + arow * 128 + ((sac ^ (arow & 7)) * 16)) = w;
    }
    __syncthreads();
#pragma unroll
    for (int ks = 0; ks < 2; ++ks) {
      bf16x8 af[4], bfv[4];
#pragma unroll
      for (int mi = 0; mi < 4; ++mi) {
        const int r = wr * 64 + mi * 16 + lrow;
        af[mi] = *(const bf16x8*)((const char*)As + r * 128 + (((ks * 4 + lk) ^ (r & 7)) * 16));
      }
#pragma unroll
      for (int ni = 0; ni < 4; ++ni) {
        const int r = wc * 64 + ni * 16 + lrow;
        bfv[ni] = *(const bf16x8*)((const char*)Bs + r * 128 + (((ks * 4 + lk) ^ (r & 7)) * 16));
      }
#pragma unroll
      for (int mi = 0; mi < 4; ++mi)
#pragma unroll
        for (int ni = 0; ni < 4; ++ni)
          acc[mi][ni] =
              __builtin_amdgcn_mfma_f32_16x16x32_bf16(af[mi], bfv[ni], acc[mi][ni], 0, 0, 0);
    }
  }
  // epilogue
  const int r0 = lane >> 4;
#pragma unroll
  for (int ni = 0; ni < 4; ++ni) {
    const int col = n0 + wc * 64 + ni * 16 + lrow;
    float bsv;
    unsigned short* Cp = C1;
    int ccol = col;
    if (MODE == 0) {
      if (col < 1024) {
        bsv = bias1[col];
      } else {
        bsv = bias2[col - 1024];
        Cp = C2;
        ccol = col - 1024;
      }
    } else {
      bsv = bias1[col];
    }
#pragma unroll
    for (int mi = 0; mi < 4; ++mi) {
      const int row = m0 + wr * 64 + mi * 16 + r0 * 4;
#pragma unroll
      for (int r = 0; r < 4; ++r) {
        float v = acc[mi][ni][r] + bsv;
        if (MODE == 0) {
          Cp[(size_t)(row + r) * 1024 + ccol] = f2bf(v);
        } else {
          const int gr = row + r;
          if ((gr & 2047) < 1985) {
            OUT[(size_t)(gr + 63) * 1024 + col] += v;
          }
        }
      }
    }
  }
}

// ---------- attention per (b,c,h): 64 queries x 256 keys ----------
__global__ __launch_bounds__(256) void attn_kernel(
    const unsigned short* __restrict__ Q, const unsigned short* __restrict__ K,
    const unsigned short* __restrict__ V, float* __restrict__ O) {
  __shared__ unsigned short k_lds[256 * 64];  // [j][d] swizzled, later reused for P
  __shared__ unsigned short v_t[64 * 256];    // [d][j] swizzled
  const int bid = blockIdx.x;
  const int h = bid & 15;
  const int bc = bid >> 4;  // b*32 + c
  const int tid = threadIdx.x;
  const int lane = tid & 63;
  const int wid = tid >> 6;
  const size_t kv0 = (size_t)bc * 256 * 1024 + h * 64;

  // Q fragments straight from global (wave wid owns query rows wid*16..+15)
  bf16x8 qf[2];
  {
    const size_t qrow = (size_t)bc * 64 + wid * 16 + (lane & 15);
    const unsigned short* qp = Q + qrow * 1024 + h * 64 + (lane >> 4) * 8;
    qf[0] = *(const bf16x8*)(qp);
    qf[1] = *(const bf16x8*)(qp + 32);
  }
  // stage K: [256][64] bf16, 128B rows, chunk XOR-swizzle
#pragma unroll
  for (int it = 0; it < 8; ++it) {
    const int j = it * 32 + (tid >> 3);
    const int c = tid & 7;
    const uint4 kv = *(const uint4*)(K + kv0 + (size_t)j * 1024 + c * 8);
    *(uint4*)((char*)k_lds + j * 128 + ((c ^ (j & 7)) * 16)) = kv;
  }
  // stage V transposed: v_t[d][j], packing (j, j+1) pairs into b32 writes
  {
    const int j = (tid >> 1) * 2;
    const int half = tid & 1;
#pragma unroll
    for (int cc2 = 0; cc2 < 4; ++cc2) {
      const int chunk = half * 4 + cc2;
      const int d0 = chunk * 8;
      u16x8 a = *(const u16x8*)(V + kv0 + (size_t)j * 1024 + d0);
      u16x8 b = *(const u16x8*)(V + kv0 + (size_t)(j + 1) * 1024 + d0);
#pragma unroll
      for (int dd = 0; dd < 8; ++dd) {
        const int d = d0 + dd;
        unsigned int p = (unsigned int)a[dd] | ((unsigned int)b[dd] << 16);
        *(unsigned int*)((char*)v_t + d * 512 + (((j >> 3) ^ (d & 7)) * 16) + ((j & 7) * 2)) = p;
      }
    }
  }
  __syncthreads();

  // S = Q K^T : lane holds S[i=(l>>4)*4+r][j=jt*16+(l&15)]
  f32x4 accs[16] = {};
#pragma unroll
  for (int jt = 0; jt < 16; ++jt) {
#pragma unroll
    for (int ks = 0; ks < 2; ++ks) {
      const int r = jt * 16 + (lane & 15);
      bf16x8 kf = *(const bf16x8*)((const char*)k_lds + r * 128 +
                                   (((ks * 4 + (lane >> 4)) ^ (r & 7)) * 16));
      accs[jt] = __builtin_amdgcn_mfma_f32_16x16x32_bf16(qf[ks], kf, accs[jt], 0, 0, 0);
    }
  }
  __syncthreads();  // everyone done reading k_lds before P overwrites it

  // softmax over 256 j (scale 1/8): reduce 16 regs in-lane + shfl_xor over 16-lane j-group
  float inv_[4];
#pragma unroll
  for (int r = 0; r < 4; ++r) {
    float m = accs[0][r];
#pragma unroll
    for (int jt = 1; jt < 16; ++jt) m = fmaxf(m, accs[jt][r]);
#pragma unroll
    for (int mk = 1; mk < 16; mk <<= 1) m = fmaxf(m, __shfl_xor(m, mk));
    float s = 0.f;
#pragma unroll
    for (int jt = 0; jt < 16; ++jt) {
      float p = __expf((accs[jt][r] - m) * 0.125f);
      accs[jt][r] = p;
      s += p;
    }
#pragma unroll
    for (int mk = 1; mk < 16; mk <<= 1) s += __shfl_xor(s, mk);
    inv_[r] = 1.0f / s;
  }
  // write P (bf16) into per-wave 8KB slice of k_lds, swizzled [16][256]
  char* pbase = (char*)k_lds + wid * 8192;
  {
    const int jc = lane & 15;
    const int i0 = (lane >> 4) * 4;
#pragma unroll
    for (int jt = 0; jt < 16; ++jt) {
      const int j = jt * 16 + jc;
#pragma unroll
      for (int r = 0; r < 4; ++r) {
        const int i = i0 + r;
        *(unsigned short*)(pbase + i * 512 + (((j >> 3) ^ (i & 7)) * 16) + ((j & 7) * 2)) =
            f2bf(accs[jt][r] * inv_[r]);
      }
    }
  }
  __syncthreads();

  // O = P V
  f32x4 acco[4] = {};
#pragma unroll
  for (int jb = 0; jb < 8; ++jb) {
    const int i = lane & 15;
    bf16x8 pf =
        *(const bf16x8*)(pbase + i * 512 + (((jb * 4 + (lane >> 4)) ^ (i & 7)) * 16));
#pragma unroll
    for (int ni = 0; ni < 4; ++ni) {
      const int d = ni * 16 + (lane & 15);
      bf16x8 vf = *(const bf16x8*)((const char*)v_t + d * 512 +
                                   (((jb * 4 + (lane >> 4)) ^ (d & 7)) * 16));
      acco[ni] = __builtin_amdgcn_mfma_f32_16x16x32_bf16(pf, vf, acco[ni], 0, 0, 0);
    }
  }
  {
    const size_t row0 = (size_t)bc * 64 + wid * 16 + (lane >> 4) * 4;
#pragma unroll
    for (int ni = 0; ni < 4; ++ni) {
      const int col = h * 64 + ni * 16 + (lane & 15);
#pragma unroll
      for (int r = 0; r < 4; ++r) {
        O[(row0 + r) * 1024 + col] = acco[ni][r];
      }
    }
  }
}

extern "C" void kernel_launch(void* const* d_in, const int* in_sizes, int n_in,
                              void* d_out, int out_size, void* d_ws, size_t ws_size,
                              hipStream_t stream) {
  const float* h = (const float*)d_in[0];
  const float* e = (const float*)d_in[1];
  const float* Wq = (const float*)d_in[2];
  const float* bq = (const float*)d_in[3];
  const float* Wk = (const float*)d_in[4];
  const float* bk = (const float*)d_in[5];
  const float* Wv = (const float*)d_in[6];
  const float* bv = (const float*)d_in[7];
  const float* gamma = (const float*)d_in[8];
  const float* beta = (const float*)d_in[9];
  const float* Wo = (const float*)d_in[10];
  const float* bo = (const float*)d_in[11];
  float* out = (float*)d_out;

  char* ws = (char*)d_ws;
  float* x = (float*)ws;                                          // 64MB (reused as o)
  unsigned short* q = (unsigned short*)(ws + (64ull << 20));      // 32MB
  unsigned short* kbuf = (unsigned short*)(ws + (96ull << 20));   // 128MB
  unsigned short* vbuf = (unsigned short*)(ws + (224ull << 20));  // 128MB
  unsigned short* wqT = (unsigned short*)(ws + (352ull << 20));   // 2MB
  unsigned short* wkvT = (unsigned short*)(ws + (354ull << 20));  // 4MB
  unsigned short* woT = (unsigned short*)(ws + (358ull << 20));   // 2MB
  float* o = x;  // x consumed by Q-GEMM before attention writes o

  // out = h (residual baseline; rows t<63 stay h)
  hipMemcpyAsync(out, h, (size_t)16384 * 1024 * 4, hipMemcpyDeviceToDevice, stream);

  dim3 tb(256);
  transpose_w<<<dim3(16, 16), tb, 0, stream>>>(Wq, wqT);
  transpose_w<<<dim3(16, 16), tb, 0, stream>>>(Wk, wkvT);
  transpose_w<<<dim3(16, 16), tb, 0, stream>>>(Wv, wkvT + 1024 * 1024);
  transpose_w<<<dim3(16, 16), tb, 0, stream>>>(Wo, woT);
  ln_kernel<<<16384, tb, 0, stream>>>(h, gamma, beta, x);
  // Q = x @ Wq + bq
  gemm128<0><<<dim3(8, 128), tb, 0, stream>>>(x, wqT, bq, nullptr, q, nullptr, nullptr);
  // [K|V] = e @ [Wk|Wv] + [bk|bv]
  gemm128<0><<<dim3(16, 512), tb, 0, stream>>>(e, wkvT, bk, bv, kbuf, vbuf, nullptr);
  // attention
  attn_kernel<<<4096, tb, 0, stream>>>(q, kbuf, vbuf, o);
  // out += shift63(o @ Wo + bo)
  gemm128<1><<<dim3(8, 128), tb, 0, stream>>>(o, woT, bo, nullptr, nullptr, nullptr, out);
}

// Round 2
// 790.222 us; speedup vs baseline: 1.1856x; 1.1856x over previous
//
#include <hip/hip_runtime.h>
#include <hip/hip_bf16.h>

typedef __attribute__((ext_vector_type(8))) short bf16x8;
typedef __attribute__((ext_vector_type(4))) float f32x4;
typedef __attribute__((ext_vector_type(8))) unsigned short u16x8;

static __device__ __forceinline__ unsigned short f2bf(float f) {
  unsigned int u = __builtin_bit_cast(unsigned int, f);
  u += 0x7fffu + ((u >> 16) & 1u);
  return (unsigned short)(u >> 16);
}
static __device__ __forceinline__ unsigned int pk2(float lo, float hi) {
  return (unsigned int)f2bf(lo) | ((unsigned int)f2bf(hi) << 16);
}
static __device__ __forceinline__ void gload_lds16(const void* g, void* l) {
  __builtin_amdgcn_global_load_lds(
      (__attribute__((address_space(1))) void*)(g),
      (__attribute__((address_space(3))) void*)(l), 16, 0, 0);
}

// ---------- f32 -> bf16 bulk convert (8 elems/thread/iter) ----------
__global__ __launch_bounds__(256) void cvt_bf16(const float* __restrict__ in,
                                                unsigned short* __restrict__ out,
                                                long n8) {
  const long stride = (long)gridDim.x * 256;
  for (long i = (long)blockIdx.x * 256 + threadIdx.x; i < n8; i += stride) {
    const float4 a = ((const float4*)in)[2 * i];
    const float4 b = ((const float4*)in)[2 * i + 1];
    uint4 w;
    w.x = pk2(a.x, a.y);
    w.y = pk2(a.z, a.w);
    w.z = pk2(b.x, b.y);
    w.w = pk2(b.z, b.w);
    ((uint4*)out)[i] = w;
  }
}

// ---------- transpose 1024x1024 f32 (K x N) -> bf16 (N x K) ----------
__global__ __launch_bounds__(256) void transpose_w(const float* __restrict__ W,
                                                   unsigned short* __restrict__ WT) {
  __shared__ float tile[64][65];
  const int bx = blockIdx.x;  // n tile
  const int by = blockIdx.y;  // k tile
  const int t = threadIdx.x;
  const int rr = t >> 6;  // 0..3
  const int cc = t & 63;
#pragma unroll
  for (int i = 0; i < 16; ++i) {
    int r = i * 4 + rr;
    tile[r][cc] = W[(size_t)(by * 64 + r) * 1024 + bx * 64 + cc];
  }
  __syncthreads();
#pragma unroll
  for (int i = 0; i < 16; ++i) {
    int n = i * 4 + rr;
    WT[(size_t)(bx * 64 + n) * 1024 + by * 64 + cc] = f2bf(tile[cc][n]);
  }
}

// ---------- LayerNorm of h[b, t+63] -> x[b, t] (bf16), pad rows t>=1985 zero ----------
__global__ __launch_bounds__(256) void ln_kernel(const float* __restrict__ H,
                                                 const float* __restrict__ gamma,
                                                 const float* __restrict__ beta,
                                                 unsigned short* __restrict__ X) {
  const int row = blockIdx.x;  // 0..16383
  const int b = row >> 11;
  const int t = row & 2047;
  const int tid = threadIdx.x;
  uint2* xo = (uint2*)(X + (size_t)row * 1024);
  if (t >= 1985) {
    uint2 z;
    z.x = 0;
    z.y = 0;
    xo[tid] = z;
    return;
  }
  const float4* hp = (const float4*)(H + (size_t)(b * 2048 + t + 63) * 1024);
  float4 v = hp[tid];
  float s = v.x + v.y + v.z + v.w;
  float q = v.x * v.x + v.y * v.y + v.z * v.z + v.w * v.w;
#pragma unroll
  for (int off = 32; off > 0; off >>= 1) {
    s += __shfl_down(s, off);
    q += __shfl_down(q, off);
  }
  __shared__ float red[8];
  const int lane = tid & 63, wid = tid >> 6;
  if (lane == 0) {
    red[wid] = s;
    red[4 + wid] = q;
  }
  __syncthreads();
  s = red[0] + red[1] + red[2] + red[3];
  q = red[4] + red[5] + red[6] + red[7];
  const float mu = s * (1.0f / 1024.0f);
  const float var = q * (1.0f / 1024.0f) - mu * mu;
  const float rs = rsqrtf(var + 1e-5f);
  const float4 g = ((const float4*)gamma)[tid];
  const float4 bb = ((const float4*)beta)[tid];
  uint2 w;
  w.x = pk2((v.x - mu) * rs * g.x + bb.x, (v.y - mu) * rs * g.y + bb.y);
  w.y = pk2((v.z - mu) * rs * g.z + bb.z, (v.w - mu) * rs * g.w + bb.w);
  xo[tid] = w;
}

// ---------- copy rows t<63 of each batch: out = h ----------
__global__ __launch_bounds__(256) void fill_head(const float* __restrict__ H,
                                                 float* __restrict__ OUT) {
  const int idx = blockIdx.x * 256 + threadIdx.x;  // 129024 float4s
  const int b = idx / 16128;
  const int rem = idx - b * 16128;
  const size_t off = (size_t)b * 524288 + rem;  // float4 units
  ((float4*)OUT)[off] = ((const float4*)H)[off];
}

// ---------- GEMM: C[M x N] = A[M x 1024] @ BT[N x 1024]^T + bias ----------
// AF32=0: A bf16, global_load_lds both sides. AF32=1: A f32 register-staged.
// MODE 0: write bf16 to C1 (col<1024) / C2 (col>=1024)
// MODE 1: OUT[(row+63)*1024+col] = H[same] + acc + bias1[col], only (row&2047)<1985
template <int MODE, int AF32>
__global__ __launch_bounds__(256) void gemm128(
    const void* __restrict__ Av, const unsigned short* __restrict__ BT,
    const float* __restrict__ bias1, const float* __restrict__ bias2,
    unsigned short* __restrict__ C1, unsigned short* __restrict__ C2,
    const float* __restrict__ H, float* __restrict__ OUT) {
  __shared__ alignas(16) unsigned short As[128 * 64];
  __shared__ alignas(16) unsigned short Bs[128 * 64];
  const int tid = threadIdx.x;
  const int lane = tid & 63;
  const int wid = tid >> 6;

  // bijective XCD swizzle (all grids are multiples of 8)
  const int nx = gridDim.x;
  const int orig = blockIdx.y * nx + blockIdx.x;
  const int cpx = (nx * gridDim.y) >> 3;
  const int swz = (orig & 7) * cpx + (orig >> 3);
  const int m0 = (swz / nx) * 128;
  const int n0 = (swz % nx) * 128;

  const int wr = wid >> 1, wc = wid & 1;
  const int lrow = lane & 15;
  const int lk = lane >> 4;

  f32x4 acc[4][4] = {};

  const int sar = tid >> 3;   // 0..31 (f32 staging)
  const int sac = tid & 7;    // logical k-chunk
  const int brl = lane >> 3;  // 0..7
  const int bcl = lane & 7;

  for (int k0 = 0; k0 < 1024; k0 += 64) {
    __syncthreads();
    // B tile: global_load_lds, pre-swizzled source so linear LDS == swizzled layout
#pragma unroll
    for (int is = 0; is < 4; ++is) {
      const int brow = is * 32 + wid * 8 + brl;
      const int bchunk = bcl ^ (brow & 7);
      gload_lds16(BT + (size_t)(n0 + brow) * 1024 + k0 + bchunk * 8,
                  (char*)Bs + (is * 32 + wid * 8) * 128);
    }
    if (AF32) {
      const float* A = (const float*)Av;
#pragma unroll
      for (int is = 0; is < 4; ++is) {
        const int arow = is * 32 + sar;
        const float4* src = (const float4*)(A + (size_t)(m0 + arow) * 1024 + k0 + sac * 8);
        float4 f0 = src[0];
        float4 f1 = src[1];
        uint4 w;
        w.x = pk2(f0.x, f0.y);
        w.y = pk2(f0.z, f0.w);
        w.z = pk2(f1.x, f1.y);
        w.w = pk2(f1.z, f1.w);
        *(uint4*)((char*)As + arow * 128 + ((sac ^ (arow & 7)) * 16)) = w;
      }
    } else {
      const unsigned short* A = (const unsigned short*)Av;
#pragma unroll
      for (int is = 0; is < 4; ++is) {
        const int arow = is * 32 + wid * 8 + brl;
        const int achunk = bcl ^ (arow & 7);
        gload_lds16(A + (size_t)(m0 + arow) * 1024 + k0 + achunk * 8,
                    (char*)As + (is * 32 + wid * 8) * 128);
      }
    }
    __syncthreads();
#pragma unroll
    for (int ks = 0; ks < 2; ++ks) {
      bf16x8 af[4], bfv[4];
#pragma unroll
      for (int mi = 0; mi < 4; ++mi) {
        const int r = wr * 64 + mi * 16 + lrow;
        af[mi] = *(const bf16x8*)((const char*)As + r * 128 + (((ks * 4 + lk) ^ (r & 7)) * 16));
      }
#pragma unroll
      for (int ni = 0; ni < 4; ++ni) {
        const int r = wc * 64 + ni * 16 + lrow;
        bfv[ni] = *(const bf16x8*)((const char*)Bs + r * 128 + (((ks * 4 + lk) ^ (r & 7)) * 16));
      }
#pragma unroll
      for (int mi = 0; mi < 4; ++mi)
#pragma unroll
        for (int ni = 0; ni < 4; ++ni)
          acc[mi][ni] =
              __builtin_amdgcn_mfma_f32_16x16x32_bf16(af[mi], bfv[ni], acc[mi][ni], 0, 0, 0);
    }
  }
  // epilogue
  const int r0 = lane >> 4;
#pragma unroll
  for (int ni = 0; ni < 4; ++ni) {
    const int col = n0 + wc * 64 + ni * 16 + lrow;
    float bsv;
    unsigned short* Cp = C1;
    int ccol = col;
    if (MODE == 0) {
      if (col < 1024) {
        bsv = bias1[col];
      } else {
        bsv = bias2[col - 1024];
        Cp = C2;
        ccol = col - 1024;
      }
    } else {
      bsv = bias1[col];
    }
#pragma unroll
    for (int mi = 0; mi < 4; ++mi) {
      const int row = m0 + wr * 64 + mi * 16 + r0 * 4;
#pragma unroll
      for (int r = 0; r < 4; ++r) {
        float v = acc[mi][ni][r] + bsv;
        if (MODE == 0) {
          Cp[(size_t)(row + r) * 1024 + ccol] = f2bf(v);
        } else {
          const int gr = row + r;
          if ((gr & 2047) < 1985) {
            const size_t idx = (size_t)(gr + 63) * 1024 + col;
            OUT[idx] = H[idx] + v;
          }
        }
      }
    }
  }
}

// ---------- attention per (b,c,h): 64 queries x 256 keys ----------
__global__ __launch_bounds__(256) void attn_kernel(
    const unsigned short* __restrict__ Q, const unsigned short* __restrict__ K,
    const unsigned short* __restrict__ V, unsigned short* __restrict__ O) {
  __shared__ alignas(16) unsigned short k_lds[256 * 64];  // [j][d] swizzled, reused for P
  __shared__ alignas(16) unsigned short v_t[64 * 256];    // [d][j] swizzled
  const int bid = blockIdx.x;
  const int h = bid & 15;
  const int bc = bid >> 4;  // b*32 + c
  const int tid = threadIdx.x;
  const int lane = tid & 63;
  const int wid = tid >> 6;
  const size_t kv0 = (size_t)bc * 256 * 1024 + h * 64;

  bf16x8 qf[2];
  {
    const size_t qrow = (size_t)bc * 64 + wid * 16 + (lane & 15);
    const unsigned short* qp = Q + qrow * 1024 + h * 64 + (lane >> 4) * 8;
    qf[0] = *(const bf16x8*)(qp);
    qf[1] = *(const bf16x8*)(qp + 32);
  }
#pragma unroll
  for (int it = 0; it < 8; ++it) {
    const int j = it * 32 + (tid >> 3);
    const int c = tid & 7;
    const uint4 kv = *(const uint4*)(K + kv0 + (size_t)j * 1024 + c * 8);
    *(uint4*)((char*)k_lds + j * 128 + ((c ^ (j & 7)) * 16)) = kv;
  }
  {
    const int j = (tid >> 1) * 2;
    const int half = tid & 1;
#pragma unroll
    for (int cc2 = 0; cc2 < 4; ++cc2) {
      const int chunk = half * 4 + cc2;
      const int d0 = chunk * 8;
      u16x8 a = *(const u16x8*)(V + kv0 + (size_t)j * 1024 + d0);
      u16x8 b = *(const u16x8*)(V + kv0 + (size_t)(j + 1) * 1024 + d0);
#pragma unroll
      for (int dd = 0; dd < 8; ++dd) {
        const int d = d0 + dd;
        unsigned int p = (unsigned int)a[dd] | ((unsigned int)b[dd] << 16);
        *(unsigned int*)((char*)v_t + d * 512 + (((j >> 3) ^ (d & 7)) * 16) + ((j & 7) * 2)) = p;
      }
    }
  }
  __syncthreads();

  f32x4 accs[16] = {};
#pragma unroll
  for (int jt = 0; jt < 16; ++jt) {
#pragma unroll
    for (int ks = 0; ks < 2; ++ks) {
      const int r = jt * 16 + (lane & 15);
      bf16x8 kf = *(const bf16x8*)((const char*)k_lds + r * 128 +
                                   (((ks * 4 + (lane >> 4)) ^ (r & 7)) * 16));
      accs[jt] = __builtin_amdgcn_mfma_f32_16x16x32_bf16(qf[ks], kf, accs[jt], 0, 0, 0);
    }
  }
  __syncthreads();

  float inv_[4];
#pragma unroll
  for (int r = 0; r < 4; ++r) {
    float m = accs[0][r];
#pragma unroll
    for (int jt = 1; jt < 16; ++jt) m = fmaxf(m, accs[jt][r]);
#pragma unroll
    for (int mk = 1; mk < 16; mk <<= 1) m = fmaxf(m, __shfl_xor(m, mk));
    float s = 0.f;
#pragma unroll
    for (int jt = 0; jt < 16; ++jt) {
      float p = __expf((accs[jt][r] - m) * 0.125f);
      accs[jt][r] = p;
      s += p;
    }
#pragma unroll
    for (int mk = 1; mk < 16; mk <<= 1) s += __shfl_xor(s, mk);
    inv_[r] = 1.0f / s;
  }
  char* pbase = (char*)k_lds + wid * 8192;
  {
    const int jc = lane & 15;
    const int i0 = (lane >> 4) * 4;
#pragma unroll
    for (int jt = 0; jt < 16; ++jt) {
      const int j = jt * 16 + jc;
#pragma unroll
      for (int r = 0; r < 4; ++r) {
        const int i = i0 + r;
        *(unsigned short*)(pbase + i * 512 + (((j >> 3) ^ (i & 7)) * 16) + ((j & 7) * 2)) =
            f2bf(accs[jt][r] * inv_[r]);
      }
    }
  }
  __syncthreads();

  f32x4 acco[4] = {};
#pragma unroll
  for (int jb = 0; jb < 8; ++jb) {
    const int i = lane & 15;
    bf16x8 pf = *(const bf16x8*)(pbase + i * 512 + (((jb * 4 + (lane >> 4)) ^ (i & 7)) * 16));
#pragma unroll
    for (int ni = 0; ni < 4; ++ni) {
      const int d = ni * 16 + (lane & 15);
      bf16x8 vf = *(const bf16x8*)((const char*)v_t + d * 512 +
                                   (((jb * 4 + (lane >> 4)) ^ (d & 7)) * 16));
      acco[ni] = __builtin_amdgcn_mfma_f32_16x16x32_bf16(pf, vf, acco[ni], 0, 0, 0);
    }
  }
  {
    const size_t row0 = (size_t)bc * 64 + wid * 16 + (lane >> 4) * 4;
#pragma unroll
    for (int ni = 0; ni < 4; ++ni) {
      const int col = h * 64 + ni * 16 + (lane & 15);
#pragma unroll
      for (int r = 0; r < 4; ++r) {
        O[(row0 + r) * 1024 + col] = f2bf(acco[ni][r]);
      }
    }
  }
}

extern "C" void kernel_launch(void* const* d_in, const int* in_sizes, int n_in,
                              void* d_out, int out_size, void* d_ws, size_t ws_size,
                              hipStream_t stream) {
  const float* h = (const float*)d_in[0];
  const float* e = (const float*)d_in[1];
  const float* Wq = (const float*)d_in[2];
  const float* bq = (const float*)d_in[3];
  const float* Wk = (const float*)d_in[4];
  const float* bk = (const float*)d_in[5];
  const float* Wv = (const float*)d_in[6];
  const float* bv = (const float*)d_in[7];
  const float* gamma = (const float*)d_in[8];
  const float* beta = (const float*)d_in[9];
  const float* Wo = (const float*)d_in[10];
  const float* bo = (const float*)d_in[11];
  float* out = (float*)d_out;

  char* ws = (char*)d_ws;
  unsigned short* x = (unsigned short*)ws;                        // 32MB (reused as o)
  unsigned short* q = (unsigned short*)(ws + (32ull << 20));      // 32MB
  unsigned short* kbuf = (unsigned short*)(ws + (64ull << 20));   // 128MB
  unsigned short* vbuf = (unsigned short*)(ws + (192ull << 20));  // 128MB
  unsigned short* ebf = (unsigned short*)(ws + (320ull << 20));   // 128MB
  unsigned short* wqT = (unsigned short*)(ws + (448ull << 20));   // 2MB
  unsigned short* wkvT = (unsigned short*)(ws + (450ull << 20));  // 4MB
  unsigned short* woT = (unsigned short*)(ws + (454ull << 20));   // 2MB
  unsigned short* o = x;  // x consumed by Q-GEMM before attention writes o

  const bool big = ws_size >= (456ull << 20);

  dim3 tb(256);
  if (big) cvt_bf16<<<2048, tb, 0, stream>>>(e, ebf, 8388608L);
  transpose_w<<<dim3(16, 16), tb, 0, stream>>>(Wq, wqT);
  transpose_w<<<dim3(16, 16), tb, 0, stream>>>(Wk, wkvT);
  transpose_w<<<dim3(16, 16), tb, 0, stream>>>(Wv, wkvT + 1024 * 1024);
  transpose_w<<<dim3(16, 16), tb, 0, stream>>>(Wo, woT);
  ln_kernel<<<16384, tb, 0, stream>>>(h, gamma, beta, x);
  // Q = x @ Wq + bq
  gemm128<0, 0><<<dim3(8, 128), tb, 0, stream>>>(x, wqT, bq, nullptr, q, nullptr, nullptr,
                                                 nullptr);
  // [K|V] = e @ [Wk|Wv] + [bk|bv]
  if (big)
    gemm128<0, 0><<<dim3(16, 512), tb, 0, stream>>>(ebf, wkvT, bk, bv, kbuf, vbuf, nullptr,
                                                    nullptr);
  else
    gemm128<0, 1><<<dim3(16, 512), tb, 0, stream>>>(e, wkvT, bk, bv, kbuf, vbuf, nullptr,
                                                    nullptr);
  // attention
  attn_kernel<<<4096, tb, 0, stream>>>(q, kbuf, vbuf, o);
  // rows t<63: out = h
  fill_head<<<504, tb, 0, stream>>>(h, out);
  // rows t>=63: out = h + shift63(o @ Wo + bo)
  gemm128<1, 0><<<dim3(8, 128), tb, 0, stream>>>(o, woT, bo, nullptr, nullptr, nullptr, h, out);
}

// Round 3
// 621.349 us; speedup vs baseline: 1.5079x; 1.2718x over previous
//
#include <hip/hip_runtime.h>
#include <hip/hip_bf16.h>

typedef __attribute__((ext_vector_type(8))) short bf16x8;
typedef __attribute__((ext_vector_type(4))) float f32x4;
typedef __attribute__((ext_vector_type(8))) unsigned short u16x8;

static __device__ __forceinline__ unsigned short f2bf(float f) {
  unsigned int u = __builtin_bit_cast(unsigned int, f);
  u += 0x7fffu + ((u >> 16) & 1u);
  return (unsigned short)(u >> 16);
}
static __device__ __forceinline__ unsigned int pk2(float lo, float hi) {
  return (unsigned int)f2bf(lo) | ((unsigned int)f2bf(hi) << 16);
}
static __device__ __forceinline__ void gload_lds16(const void* g, void* l) {
  __builtin_amdgcn_global_load_lds(
      (__attribute__((address_space(1))) void*)(g),
      (__attribute__((address_space(3))) void*)(l), 16, 0, 0);
}

// ---------- f32 -> bf16 bulk convert ----------
__global__ __launch_bounds__(256) void cvt_bf16(const float* __restrict__ in,
                                                unsigned short* __restrict__ out,
                                                long n8) {
  const long stride = (long)gridDim.x * 256;
  for (long i = (long)blockIdx.x * 256 + threadIdx.x; i < n8; i += stride) {
    const float4 a = ((const float4*)in)[2 * i];
    const float4 b = ((const float4*)in)[2 * i + 1];
    uint4 w;
    w.x = pk2(a.x, a.y);
    w.y = pk2(a.z, a.w);
    w.z = pk2(b.x, b.y);
    w.w = pk2(b.z, b.w);
    ((uint4*)out)[i] = w;
  }
}

// ---------- transpose 1024x1024 f32 (K x N) -> bf16 (N x K) ----------
__global__ __launch_bounds__(256) void transpose_w(const float* __restrict__ W,
                                                   unsigned short* __restrict__ WT) {
  __shared__ float tile[64][65];
  const int bx = blockIdx.x;
  const int by = blockIdx.y;
  const int t = threadIdx.x;
  const int rr = t >> 6;
  const int cc = t & 63;
#pragma unroll
  for (int i = 0; i < 16; ++i) {
    int r = i * 4 + rr;
    tile[r][cc] = W[(size_t)(by * 64 + r) * 1024 + bx * 64 + cc];
  }
  __syncthreads();
#pragma unroll
  for (int i = 0; i < 16; ++i) {
    int n = i * 4 + rr;
    WT[(size_t)(bx * 64 + n) * 1024 + by * 64 + cc] = f2bf(tile[cc][n]);
  }
}

// ---------- LayerNorm of h[b, t+63] -> x[b, t] (bf16), pad rows t>=1985 zero ----------
__global__ __launch_bounds__(256) void ln_kernel(const float* __restrict__ H,
                                                 const float* __restrict__ gamma,
                                                 const float* __restrict__ beta,
                                                 unsigned short* __restrict__ X) {
  const int row = blockIdx.x;
  const int b = row >> 11;
  const int t = row & 2047;
  const int tid = threadIdx.x;
  uint2* xo = (uint2*)(X + (size_t)row * 1024);
  if (t >= 1985) {
    uint2 z;
    z.x = 0;
    z.y = 0;
    xo[tid] = z;
    return;
  }
  const float4* hp = (const float4*)(H + (size_t)(b * 2048 + t + 63) * 1024);
  float4 v = hp[tid];
  float s = v.x + v.y + v.z + v.w;
  float q = v.x * v.x + v.y * v.y + v.z * v.z + v.w * v.w;
#pragma unroll
  for (int off = 32; off > 0; off >>= 1) {
    s += __shfl_down(s, off);
    q += __shfl_down(q, off);
  }
  __shared__ float red[8];
  const int lane = tid & 63, wid = tid >> 6;
  if (lane == 0) {
    red[wid] = s;
    red[4 + wid] = q;
  }
  __syncthreads();
  s = red[0] + red[1] + red[2] + red[3];
  q = red[4] + red[5] + red[6] + red[7];
  const float mu = s * (1.0f / 1024.0f);
  const float var = q * (1.0f / 1024.0f) - mu * mu;
  const float rs = rsqrtf(var + 1e-5f);
  const float4 g = ((const float4*)gamma)[tid];
  const float4 bb = ((const float4*)beta)[tid];
  uint2 w;
  w.x = pk2((v.x - mu) * rs * g.x + bb.x, (v.y - mu) * rs * g.y + bb.y);
  w.y = pk2((v.z - mu) * rs * g.z + bb.z, (v.w - mu) * rs * g.w + bb.w);
  xo[tid] = w;
}

// ---------- copy rows t<63 of each batch: out = h ----------
__global__ __launch_bounds__(256) void fill_head(const float* __restrict__ H,
                                                 float* __restrict__ OUT) {
  const int idx = blockIdx.x * 256 + threadIdx.x;
  const int b = idx / 16128;
  const int rem = idx - b * 16128;
  const size_t off = (size_t)b * 524288 + rem;
  ((float4*)OUT)[off] = ((const float4*)H)[off];
}

// ================= 256x256 8-phase GEMM (T2+T3+T4+T5) =================
// C[M x N] = A[M x 1024](bf16) @ BT[N x 1024](bf16)^T + bias, K=1024, NT=16 k-tiles.
// 512 threads = 8 waves (2M x 4N), per-wave 128x64 output.
// LDS: 2 dbuf x 4 slots {A0,A1,B0,B1}, slot = 128 rows x 64 k (16KB). 128 KiB total.
// Per 2-k-tile iteration, 8 phases; 1 slot staged/phase; vmcnt(2) at P4/P8 only.
#define MIDBAR()                                           \
  {                                                        \
    __builtin_amdgcn_s_barrier();                          \
    asm volatile("s_waitcnt lgkmcnt(0)" ::: "memory");     \
  }
#define ENDBAR() __builtin_amdgcn_s_barrier()
#define VMW2() asm volatile("s_waitcnt vmcnt(2)" ::: "memory")

#define LDA_(mh, buf)                                                                   \
  {                                                                                     \
    const char* base_ = (const char*)&lds[buf][wm][0];                                  \
    _Pragma("unroll") for (int mi = 0; mi < 4; ++mi) {                                  \
      const int r_ = (mh) * 64 + mi * 16 + lrow;                                        \
      af[mi][0] = *(const bf16x8*)(base_ + r_ * 128 + (((0 + lk) ^ (r_ & 7)) * 16));    \
      af[mi][1] = *(const bf16x8*)(base_ + r_ * 128 + (((4 + lk) ^ (r_ & 7)) * 16));    \
    }                                                                                   \
  }
#define LDB_(nh, buf)                                                                   \
  {                                                                                     \
    const char* base_ = (const char*)&lds[buf][2 + (wn >> 1)][0];                       \
    _Pragma("unroll") for (int ni = 0; ni < 2; ++ni) {                                  \
      const int r_ = (wn & 1) * 64 + (nh) * 32 + ni * 16 + lrow;                        \
      bfr[ni][0] = *(const bf16x8*)(base_ + r_ * 128 + (((0 + lk) ^ (r_ & 7)) * 16));   \
      bfr[ni][1] = *(const bf16x8*)(base_ + r_ * 128 + (((4 + lk) ^ (r_ & 7)) * 16));   \
    }                                                                                   \
  }
#define MMA_(mh, nh)                                                                    \
  {                                                                                     \
    __builtin_amdgcn_s_setprio(1);                                                      \
    _Pragma("unroll") for (int mi = 0; mi < 4; ++mi)                                    \
        _Pragma("unroll") for (int ni = 0; ni < 2; ++ni) {                              \
      acc[(mh) * 4 + mi][(nh) * 2 + ni] = __builtin_amdgcn_mfma_f32_16x16x32_bf16(      \
          af[mi][0], bfr[ni][0], acc[(mh) * 4 + mi][(nh) * 2 + ni], 0, 0, 0);           \
      acc[(mh) * 4 + mi][(nh) * 2 + ni] = __builtin_amdgcn_mfma_f32_16x16x32_bf16(      \
          af[mi][1], bfr[ni][1], acc[(mh) * 4 + mi][(nh) * 2 + ni], 0, 0, 0);           \
    }                                                                                   \
    __builtin_amdgcn_s_setprio(0);                                                      \
  }

template <int MODE>
__global__ __launch_bounds__(512, 2) void gemm256(
    const unsigned short* __restrict__ A, const unsigned short* __restrict__ BT,
    const float* __restrict__ bias1, const float* __restrict__ bias2,
    unsigned short* __restrict__ C1, unsigned short* __restrict__ C2,
    const float* __restrict__ H, float* __restrict__ OUT) {
  __shared__ alignas(16) unsigned short lds[2][4][128 * 64];
  const int tid = threadIdx.x;
  const int lane = tid & 63;
  const int wid = tid >> 6;
  const int wm = wid >> 2, wn = wid & 3;
  const int lrow = lane & 15, lk = lane >> 4;

  const int nx = gridDim.x;
  const int orig = blockIdx.y * nx + blockIdx.x;
  const int cpx = (nx * gridDim.y) >> 3;
  const int swz = (orig & 7) * cpx + (orig >> 3);
  const int m0 = (swz / nx) * 256;
  const int n0 = (swz % nx) * 256;

  f32x4 acc[8][4] = {};
  bf16x8 af[4][2], bfr[2][2];

  // stage slot s (0=A0,1=A1,2=B0,3=B1) of k-tile kt into lds[kt&1][s].
  // dest: wave-uniform base + lane*16 (linear); src pre-swizzled (chunk ^ row&7).
  auto STAGE = [&](int slot, int kt) {
    const int buf = kt & 1;
    const int kc = kt < 16 ? kt : 15;  // clamp: keeps per-wave vmcnt counts uniform
    const unsigned short* src = (slot < 2) ? A + (size_t)(m0 + slot * 128) * 1024
                                           : BT + (size_t)(n0 + (slot - 2) * 128) * 1024;
    unsigned short* dst = &lds[buf][slot][0];
#pragma unroll
    for (int l = 0; l < 2; ++l) {
      const int row = l * 64 + wid * 8 + (lane >> 3);
      const int ch = (lane & 7) ^ (row & 7);
      gload_lds16(src + (size_t)row * 1024 + kc * 64 + ch * 8,
                  (char*)dst + (l * 64 + wid * 8) * 128);
    }
  };

  // prologue: tile0 (4 slots) + tile1.A0; drain tile0 (10 outstanding -> 2)
  STAGE(0, 0);
  STAGE(1, 0);
  STAGE(2, 0);
  STAGE(3, 0);
  STAGE(0, 1);
  VMW2();
  __builtin_amdgcn_s_barrier();

  for (int it = 0; it < 8; ++it) {
    const int t = 2 * it;
    // P1: reads tile t (buf0) A-half0 + B-half0
    LDA_(0, 0);
    LDB_(0, 0);
    STAGE(1, t + 1);
    MIDBAR();
    MMA_(0, 0);
    ENDBAR();
    // P2
    LDB_(1, 0);
    STAGE(2, t + 1);
    MIDBAR();
    MMA_(0, 1);
    ENDBAR();
    // P3
    LDA_(1, 0);
    STAGE(3, t + 1);
    MIDBAR();
    MMA_(1, 1);
    ENDBAR();
    // P4: vmcnt(2) drains all 4 slots of tile t+1 (leaves A0(t+2) in flight)
    LDB_(0, 0);
    STAGE(0, t + 2);
    MIDBAR();
    MMA_(1, 0);
    VMW2();
    ENDBAR();
    // P5: tile t+1 (buf1)
    LDA_(0, 1);
    LDB_(0, 1);
    STAGE(1, t + 2);
    MIDBAR();
    MMA_(0, 0);
    ENDBAR();
    // P6
    LDB_(1, 1);
    STAGE(2, t + 2);
    MIDBAR();
    MMA_(0, 1);
    ENDBAR();
    // P7
    LDA_(1, 1);
    STAGE(3, t + 2);
    MIDBAR();
    MMA_(1, 1);
    ENDBAR();
    // P8: vmcnt(2) drains tile t+2's 4 slots
    LDB_(0, 1);
    STAGE(0, t + 3);
    MIDBAR();
    MMA_(1, 0);
    VMW2();
    ENDBAR();
  }

  // epilogue
  const int r0 = lane >> 4;
#pragma unroll
  for (int N = 0; N < 4; ++N) {
    const int col = n0 + wn * 64 + N * 16 + lrow;
    float bsv;
    unsigned short* Cp = C1;
    int ccol = col;
    if (MODE == 0) {
      if (col < 1024) {
        bsv = bias1[col];
      } else {
        bsv = bias2[col - 1024];
        Cp = C2;
        ccol = col - 1024;
      }
    } else {
      bsv = bias1[col];
    }
#pragma unroll
    for (int M = 0; M < 8; ++M) {
      const int row = m0 + wm * 128 + M * 16 + r0 * 4;
#pragma unroll
      for (int r = 0; r < 4; ++r) {
        float v = acc[M][N][r] + bsv;
        if (MODE == 0) {
          Cp[(size_t)(row + r) * 1024 + ccol] = f2bf(v);
        } else {
          const int gr = row + r;
          if ((gr & 2047) < 1985) {
            const size_t idx = (size_t)(gr + 63) * 1024 + col;
            OUT[idx] = H[idx] + v;
          }
        }
      }
    }
  }
}

// ---------- attention per (b,c,h): 64 queries x 256 keys ----------
__global__ __launch_bounds__(256) void attn_kernel(
    const unsigned short* __restrict__ Q, const unsigned short* __restrict__ K,
    const unsigned short* __restrict__ V, unsigned short* __restrict__ O) {
  __shared__ alignas(16) unsigned short k_lds[256 * 64];
  __shared__ alignas(16) unsigned short v_t[64 * 256];
  const int bid = blockIdx.x;
  const int h = bid & 15;
  const int bc = bid >> 4;
  const int tid = threadIdx.x;
  const int lane = tid & 63;
  const int wid = tid >> 6;
  const size_t kv0 = (size_t)bc * 256 * 1024 + h * 64;

  bf16x8 qf[2];
  {
    const size_t qrow = (size_t)bc * 64 + wid * 16 + (lane & 15);
    const unsigned short* qp = Q + qrow * 1024 + h * 64 + (lane >> 4) * 8;
    qf[0] = *(const bf16x8*)(qp);
    qf[1] = *(const bf16x8*)(qp + 32);
  }
#pragma unroll
  for (int it = 0; it < 8; ++it) {
    const int j = it * 32 + (tid >> 3);
    const int c = tid & 7;
    const uint4 kv = *(const uint4*)(K + kv0 + (size_t)j * 1024 + c * 8);
    *(uint4*)((char*)k_lds + j * 128 + ((c ^ (j & 7)) * 16)) = kv;
  }
  {
    const int j = (tid >> 1) * 2;
    const int half = tid & 1;
#pragma unroll
    for (int cc2 = 0; cc2 < 4; ++cc2) {
      const int chunk = half * 4 + cc2;
      const int d0 = chunk * 8;
      u16x8 a = *(const u16x8*)(V + kv0 + (size_t)j * 1024 + d0);
      u16x8 b = *(const u16x8*)(V + kv0 + (size_t)(j + 1) * 1024 + d0);
#pragma unroll
      for (int dd = 0; dd < 8; ++dd) {
        const int d = d0 + dd;
        unsigned int p = (unsigned int)a[dd] | ((unsigned int)b[dd] << 16);
        *(unsigned int*)((char*)v_t + d * 512 + (((j >> 3) ^ (d & 7)) * 16) + ((j & 7) * 2)) = p;
      }
    }
  }
  __syncthreads();

  f32x4 accs[16] = {};
#pragma unroll
  for (int jt = 0; jt < 16; ++jt) {
#pragma unroll
    for (int ks = 0; ks < 2; ++ks) {
      const int r = jt * 16 + (lane & 15);
      bf16x8 kf = *(const bf16x8*)((const char*)k_lds + r * 128 +
                                   (((ks * 4 + (lane >> 4)) ^ (r & 7)) * 16));
      accs[jt] = __builtin_amdgcn_mfma_f32_16x16x32_bf16(qf[ks], kf, accs[jt], 0, 0, 0);
    }
  }
  __syncthreads();

  float inv_[4];
#pragma unroll
  for (int r = 0; r < 4; ++r) {
    float m = accs[0][r];
#pragma unroll
    for (int jt = 1; jt < 16; ++jt) m = fmaxf(m, accs[jt][r]);
#pragma unroll
    for (int mk = 1; mk < 16; mk <<= 1) m = fmaxf(m, __shfl_xor(m, mk));
    float s = 0.f;
#pragma unroll
    for (int jt = 0; jt < 16; ++jt) {
      float p = __expf((accs[jt][r] - m) * 0.125f);
      accs[jt][r] = p;
      s += p;
    }
#pragma unroll
    for (int mk = 1; mk < 16; mk <<= 1) s += __shfl_xor(s, mk);
    inv_[r] = 1.0f / s;
  }
  char* pbase = (char*)k_lds + wid * 8192;
  {
    const int jc = lane & 15;
    const int i0 = (lane >> 4) * 4;
#pragma unroll
    for (int jt = 0; jt < 16; ++jt) {
      const int j = jt * 16 + jc;
#pragma unroll
      for (int r = 0; r < 4; ++r) {
        const int i = i0 + r;
        *(unsigned short*)(pbase + i * 512 + (((j >> 3) ^ (i & 7)) * 16) + ((j & 7) * 2)) =
            f2bf(accs[jt][r] * inv_[r]);
      }
    }
  }
  __syncthreads();

  f32x4 acco[4] = {};
#pragma unroll
  for (int jb = 0; jb < 8; ++jb) {
    const int i = lane & 15;
    bf16x8 pf = *(const bf16x8*)(pbase + i * 512 + (((jb * 4 + (lane >> 4)) ^ (i & 7)) * 16));
#pragma unroll
    for (int ni = 0; ni < 4; ++ni) {
      const int d = ni * 16 + (lane & 15);
      bf16x8 vf = *(const bf16x8*)((const char*)v_t + d * 512 +
                                   (((jb * 4 + (lane >> 4)) ^ (d & 7)) * 16));
      acco[ni] = __builtin_amdgcn_mfma_f32_16x16x32_bf16(pf, vf, acco[ni], 0, 0, 0);
    }
  }
  {
    const size_t row0 = (size_t)bc * 64 + wid * 16 + (lane >> 4) * 4;
#pragma unroll
    for (int ni = 0; ni < 4; ++ni) {
      const int col = h * 64 + ni * 16 + (lane & 15);
#pragma unroll
      for (int r = 0; r < 4; ++r) {
        O[(row0 + r) * 1024 + col] = f2bf(acco[ni][r]);
      }
    }
  }
}

extern "C" void kernel_launch(void* const* d_in, const int* in_sizes, int n_in,
                              void* d_out, int out_size, void* d_ws, size_t ws_size,
                              hipStream_t stream) {
  const float* h = (const float*)d_in[0];
  const float* e = (const float*)d_in[1];
  const float* Wq = (const float*)d_in[2];
  const float* bq = (const float*)d_in[3];
  const float* Wk = (const float*)d_in[4];
  const float* bk = (const float*)d_in[5];
  const float* Wv = (const float*)d_in[6];
  const float* bv = (const float*)d_in[7];
  const float* gamma = (const float*)d_in[8];
  const float* beta = (const float*)d_in[9];
  const float* Wo = (const float*)d_in[10];
  const float* bo = (const float*)d_in[11];
  float* out = (float*)d_out;

  char* ws = (char*)d_ws;
  unsigned short* x = (unsigned short*)ws;                        // 32MB (reused as o)
  unsigned short* q = (unsigned short*)(ws + (32ull << 20));      // 32MB
  unsigned short* kbuf = (unsigned short*)(ws + (64ull << 20));   // 128MB
  unsigned short* vbuf = (unsigned short*)(ws + (192ull << 20));  // 128MB
  unsigned short* ebf = (unsigned short*)(ws + (320ull << 20));   // 128MB
  unsigned short* wqT = (unsigned short*)(ws + (448ull << 20));   // 2MB
  unsigned short* wkvT = (unsigned short*)(ws + (450ull << 20));  // 4MB
  unsigned short* woT = (unsigned short*)(ws + (454ull << 20));   // 2MB
  unsigned short* o = x;

  dim3 tb(256);
  cvt_bf16<<<2048, tb, 0, stream>>>(e, ebf, 8388608L);
  transpose_w<<<dim3(16, 16), tb, 0, stream>>>(Wq, wqT);
  transpose_w<<<dim3(16, 16), tb, 0, stream>>>(Wk, wkvT);
  transpose_w<<<dim3(16, 16), tb, 0, stream>>>(Wv, wkvT + 1024 * 1024);
  transpose_w<<<dim3(16, 16), tb, 0, stream>>>(Wo, woT);
  ln_kernel<<<16384, tb, 0, stream>>>(h, gamma, beta, x);
  // Q = x @ Wq + bq
  gemm256<0><<<dim3(4, 64), dim3(512), 0, stream>>>(x, wqT, bq, nullptr, q, nullptr,
                                                    nullptr, nullptr);
  // [K|V] = e @ [Wk|Wv] + [bk|bv]
  gemm256<0><<<dim3(8, 256), dim3(512), 0, stream>>>(ebf, wkvT, bk, bv, kbuf, vbuf,
                                                     nullptr, nullptr);
  // attention
  attn_kernel<<<4096, tb, 0, stream>>>(q, kbuf, vbuf, o);
  // rows t<63: out = h
  fill_head<<<504, tb, 0, stream>>>(h, out);
  // rows t>=63: out = h + shift63(o @ Wo + bo)
  gemm256<1><<<dim3(4, 64), dim3(512), 0, stream>>>(o, woT, bo, nullptr, nullptr, nullptr,
                                                    h, out);
}

// Round 4
// 569.402 us; speedup vs baseline: 1.6454x; 1.0912x over previous
//
#include <hip/hip_runtime.h>
#include <hip/hip_bf16.h>

typedef __attribute__((ext_vector_type(8))) short bf16x8;
typedef __attribute__((ext_vector_type(4))) float f32x4;
typedef __attribute__((ext_vector_type(8))) unsigned short u16x8;

static __device__ __forceinline__ unsigned short f2bf(float f) {
  unsigned int u = __builtin_bit_cast(unsigned int, f);
  u += 0x7fffu + ((u >> 16) & 1u);
  return (unsigned short)(u >> 16);
}
static __device__ __forceinline__ unsigned int pk2(float lo, float hi) {
  return (unsigned int)f2bf(lo) | ((unsigned int)f2bf(hi) << 16);
}
static __device__ __forceinline__ void gload_lds16(const void* g, void* l) {
  __builtin_amdgcn_global_load_lds(
      (__attribute__((address_space(1))) void*)(g),
      (__attribute__((address_space(3))) void*)(l), 16, 0, 0);
}

// ---------- f32 -> bf16 bulk convert ----------
__global__ __launch_bounds__(256) void cvt_bf16(const float* __restrict__ in,
                                                unsigned short* __restrict__ out,
                                                long n8) {
  const long stride = (long)gridDim.x * 256;
  for (long i = (long)blockIdx.x * 256 + threadIdx.x; i < n8; i += stride) {
    const float4 a = ((const float4*)in)[2 * i];
    const float4 b = ((const float4*)in)[2 * i + 1];
    uint4 w;
    w.x = pk2(a.x, a.y);
    w.y = pk2(a.z, a.w);
    w.z = pk2(b.x, b.y);
    w.w = pk2(b.z, b.w);
    ((uint4*)out)[i] = w;
  }
}

// ---------- transpose 1024x1024 f32 (K x N) -> bf16 (N x K) ----------
__global__ __launch_bounds__(256) void transpose_w(const float* __restrict__ W,
                                                   unsigned short* __restrict__ WT) {
  __shared__ float tile[64][65];
  const int bx = blockIdx.x;
  const int by = blockIdx.y;
  const int t = threadIdx.x;
  const int rr = t >> 6;
  const int cc = t & 63;
#pragma unroll
  for (int i = 0; i < 16; ++i) {
    int r = i * 4 + rr;
    tile[r][cc] = W[(size_t)(by * 64 + r) * 1024 + bx * 64 + cc];
  }
  __syncthreads();
#pragma unroll
  for (int i = 0; i < 16; ++i) {
    int n = i * 4 + rr;
    WT[(size_t)(bx * 64 + n) * 1024 + by * 64 + cc] = f2bf(tile[cc][n]);
  }
}

// ---------- LayerNorm of h[b, t+63] -> x[b, t] (bf16), pad rows t>=1985 zero ----------
__global__ __launch_bounds__(256) void ln_kernel(const float* __restrict__ H,
                                                 const float* __restrict__ gamma,
                                                 const float* __restrict__ beta,
                                                 unsigned short* __restrict__ X) {
  const int row = blockIdx.x;
  const int b = row >> 11;
  const int t = row & 2047;
  const int tid = threadIdx.x;
  uint2* xo = (uint2*)(X + (size_t)row * 1024);
  if (t >= 1985) {
    uint2 z;
    z.x = 0;
    z.y = 0;
    xo[tid] = z;
    return;
  }
  const float4* hp = (const float4*)(H + (size_t)(b * 2048 + t + 63) * 1024);
  float4 v = hp[tid];
  float s = v.x + v.y + v.z + v.w;
  float q = v.x * v.x + v.y * v.y + v.z * v.z + v.w * v.w;
#pragma unroll
  for (int off = 32; off > 0; off >>= 1) {
    s += __shfl_down(s, off);
    q += __shfl_down(q, off);
  }
  __shared__ float red[8];
  const int lane = tid & 63, wid = tid >> 6;
  if (lane == 0) {
    red[wid] = s;
    red[4 + wid] = q;
  }
  __syncthreads();
  s = red[0] + red[1] + red[2] + red[3];
  q = red[4] + red[5] + red[6] + red[7];
  const float mu = s * (1.0f / 1024.0f);
  const float var = q * (1.0f / 1024.0f) - mu * mu;
  const float rs = rsqrtf(var + 1e-5f);
  const float4 g = ((const float4*)gamma)[tid];
  const float4 bb = ((const float4*)beta)[tid];
  uint2 w;
  w.x = pk2((v.x - mu) * rs * g.x + bb.x, (v.y - mu) * rs * g.y + bb.y);
  w.y = pk2((v.z - mu) * rs * g.z + bb.z, (v.w - mu) * rs * g.w + bb.w);
  xo[tid] = w;
}

// ---------- copy rows t<63 of each batch: out = h ----------
__global__ __launch_bounds__(256) void fill_head(const float* __restrict__ H,
                                                 float* __restrict__ OUT) {
  const int idx = blockIdx.x * 256 + threadIdx.x;
  const int b = idx / 16128;
  const int rem = idx - b * 16128;
  const size_t off = (size_t)b * 524288 + rem;
  ((float4*)OUT)[off] = ((const float4*)H)[off];
}

// ================= 256x256 8-phase GEMM (T2+T3+T4+T5) =================
// 512 threads = 8 waves (2M x 4N), per-wave 128x64 output; BK=64, 16 k-tiles.
// LDS: 2 dbuf x 4 slots {A0,A1,B0,B1}, slot = 128 x 64 (16KB). 128 KiB.
// Per 2-tile iter: 8 phases, 1 slot staged/phase, vmcnt(2) at P4/P8 only.
// B fragments for BOTH n-halves held in regs across the 4 phases (no reread);
// P4/P8 are pure-MFMA. Barriers: fence + s_barrier + sched_barrier(0) --
// NO forced lgkmcnt(0) drain (compiler emits per-use waits -> read/MFMA overlap).
#define FENCE_BAR()                                  \
  {                                                  \
    asm volatile("" ::: "memory");                   \
    __builtin_amdgcn_s_barrier();                    \
    __builtin_amdgcn_sched_barrier(0);               \
  }
#define VMW2() asm volatile("s_waitcnt vmcnt(2)" ::: "memory")

#define LDA_(mh, buf)                                                                   \
  {                                                                                     \
    const char* base_ = (const char*)&lds[buf][wm][0];                                  \
    _Pragma("unroll") for (int mi = 0; mi < 4; ++mi) {                                  \
      const int r_ = (mh) * 64 + mi * 16 + lrow;                                        \
      af[mi][0] = *(const bf16x8*)(base_ + r_ * 128 + (((0 + lk) ^ (r_ & 7)) * 16));    \
      af[mi][1] = *(const bf16x8*)(base_ + r_ * 128 + (((4 + lk) ^ (r_ & 7)) * 16));    \
    }                                                                                   \
  }
#define LDB_(nh, buf)                                                                   \
  {                                                                                     \
    const char* base_ = (const char*)&lds[buf][2 + (wn >> 1)][0];                       \
    _Pragma("unroll") for (int ni = 0; ni < 2; ++ni) {                                  \
      const int r_ = (wn & 1) * 64 + (nh) * 32 + ni * 16 + lrow;                        \
      bfr[nh][ni][0] =                                                                  \
          *(const bf16x8*)(base_ + r_ * 128 + (((0 + lk) ^ (r_ & 7)) * 16));            \
      bfr[nh][ni][1] =                                                                  \
          *(const bf16x8*)(base_ + r_ * 128 + (((4 + lk) ^ (r_ & 7)) * 16));            \
    }                                                                                   \
  }
#define MMA_(mh, nh)                                                                    \
  {                                                                                     \
    __builtin_amdgcn_s_setprio(1);                                                      \
    _Pragma("unroll") for (int mi = 0; mi < 4; ++mi)                                    \
        _Pragma("unroll") for (int ni = 0; ni < 2; ++ni) {                              \
      acc[(mh) * 4 + mi][(nh) * 2 + ni] = __builtin_amdgcn_mfma_f32_16x16x32_bf16(      \
          af[mi][0], bfr[nh][ni][0], acc[(mh) * 4 + mi][(nh) * 2 + ni], 0, 0, 0);       \
      acc[(mh) * 4 + mi][(nh) * 2 + ni] = __builtin_amdgcn_mfma_f32_16x16x32_bf16(      \
          af[mi][1], bfr[nh][ni][1], acc[(mh) * 4 + mi][(nh) * 2 + ni], 0, 0, 0);       \
    }                                                                                   \
    __builtin_amdgcn_s_setprio(0);                                                      \
  }

template <int MODE>
__global__ __launch_bounds__(512, 2) void gemm256(
    const unsigned short* __restrict__ A, const unsigned short* __restrict__ BT,
    const float* __restrict__ bias1, const float* __restrict__ bias2,
    unsigned short* __restrict__ C1, unsigned short* __restrict__ C2,
    const float* __restrict__ H, float* __restrict__ OUT) {
  __shared__ alignas(16) unsigned short lds[2][4][128 * 64];
  const int tid = threadIdx.x;
  const int lane = tid & 63;
  const int wid = tid >> 6;
  const int wm = wid >> 2, wn = wid & 3;
  const int lrow = lane & 15, lk = lane >> 4;

  const int nx = gridDim.x;
  const int orig = blockIdx.y * nx + blockIdx.x;
  const int cpx = (nx * gridDim.y) >> 3;
  const int swz = (orig & 7) * cpx + (orig >> 3);
  const int m0 = (swz / nx) * 256;
  const int n0 = (swz % nx) * 256;

  f32x4 acc[8][4] = {};
  bf16x8 af[4][2], bfr[2][2][2];

  auto STAGE = [&](int slot, int kt) {
    const int buf = kt & 1;
    const int kc = kt < 16 ? kt : 15;
    const unsigned short* src = (slot < 2) ? A + (size_t)(m0 + slot * 128) * 1024
                                           : BT + (size_t)(n0 + (slot - 2) * 128) * 1024;
    unsigned short* dst = &lds[buf][slot][0];
#pragma unroll
    for (int l = 0; l < 2; ++l) {
      const int row = l * 64 + wid * 8 + (lane >> 3);
      const int ch = (lane & 7) ^ (row & 7);
      gload_lds16(src + (size_t)row * 1024 + kc * 64 + ch * 8,
                  (char*)dst + (l * 64 + wid * 8) * 128);
    }
  };

  // prologue: tile0 (4 slots) + tile1.A0; drain tile0
  STAGE(0, 0);
  STAGE(1, 0);
  STAGE(2, 0);
  STAGE(3, 0);
  STAGE(0, 1);
  VMW2();
  __builtin_amdgcn_s_barrier();

  for (int it = 0; it < 8; ++it) {
    const int t = 2 * it;
    // P1
    LDA_(0, 0);
    LDB_(0, 0);
    STAGE(1, t + 1);
    FENCE_BAR();
    MMA_(0, 0);
    FENCE_BAR();
    // P2
    LDB_(1, 0);
    STAGE(2, t + 1);
    FENCE_BAR();
    MMA_(0, 1);
    FENCE_BAR();
    // P3
    LDA_(1, 0);
    STAGE(3, t + 1);
    FENCE_BAR();
    MMA_(1, 1);
    FENCE_BAR();
    // P4: pure MFMA (bfr[0] held from P1); vmcnt(2) drains tile t+1 slots
    STAGE(0, t + 2);
    FENCE_BAR();
    MMA_(1, 0);
    VMW2();
    FENCE_BAR();
    // P5
    LDA_(0, 1);
    LDB_(0, 1);
    STAGE(1, t + 2);
    FENCE_BAR();
    MMA_(0, 0);
    FENCE_BAR();
    // P6
    LDB_(1, 1);
    STAGE(2, t + 2);
    FENCE_BAR();
    MMA_(0, 1);
    FENCE_BAR();
    // P7
    LDA_(1, 1);
    STAGE(3, t + 2);
    FENCE_BAR();
    MMA_(1, 1);
    FENCE_BAR();
    // P8: pure MFMA; vmcnt(2) drains tile t+2 slots
    STAGE(0, t + 3);
    FENCE_BAR();
    MMA_(1, 0);
    VMW2();
    FENCE_BAR();
  }

  if (MODE == 0) {
    // ---- LDS-bounce epilogue: coalesced bf16 stores ----
    const float* bsel = (n0 < 1024) ? bias1 : bias2;
    const int cbase = (n0 < 1024) ? n0 : (n0 - 1024);
    unsigned short* Cp0 = (n0 < 1024) ? C1 : C2;
    float bsv[4];
#pragma unroll
    for (int N = 0; N < 4; ++N) bsv[N] = bsel[cbase + wn * 64 + N * 16 + lrow];
    float* arr = (float*)&lds[0][0][0];  // [64][260] padded
    const int q4 = lane >> 4;
    __syncthreads();
#pragma unroll
    for (int p = 0; p < 4; ++p) {
      if (wm == (p >> 1)) {
#pragma unroll
        for (int mb = 0; mb < 4; ++mb) {
          const int M = (p & 1) * 4 + mb;
#pragma unroll
          for (int N = 0; N < 4; ++N) {
            const int cl = wn * 64 + N * 16 + lrow;
#pragma unroll
            for (int r = 0; r < 4; ++r) {
              arr[(mb * 16 + q4 * 4 + r) * 260 + cl] = acc[M][N][r] + bsv[N];
            }
          }
        }
      }
      __syncthreads();
#pragma unroll
      for (int k = 0; k < 4; ++k) {
        const int chunk = k * 512 + tid;
        const int row = chunk >> 5;
        const int c8 = chunk & 31;
        const float* s = arr + row * 260 + c8 * 8;
        float4 f0 = *(const float4*)(s);
        float4 f1 = *(const float4*)(s + 4);
        uint4 w;
        w.x = pk2(f0.x, f0.y);
        w.y = pk2(f0.z, f0.w);
        w.z = pk2(f1.x, f1.y);
        w.w = pk2(f1.z, f1.w);
        *(uint4*)(Cp0 + (size_t)(m0 + p * 64 + row) * 1024 + cbase + c8 * 8) = w;
      }
      __syncthreads();
    }
  } else {
    const int r0 = lane >> 4;
#pragma unroll
    for (int N = 0; N < 4; ++N) {
      const int col = n0 + wn * 64 + N * 16 + lrow;
      const float bsv = bias1[col];
#pragma unroll
      for (int M = 0; M < 8; ++M) {
        const int row = m0 + wm * 128 + M * 16 + r0 * 4;
#pragma unroll
        for (int r = 0; r < 4; ++r) {
          const int gr = row + r;
          if ((gr & 2047) < 1985) {
            const size_t idx = (size_t)(gr + 63) * 1024 + col;
            OUT[idx] = H[idx] + acc[M][N][r] + bsv;
          }
        }
      }
    }
  }
}

// ---------- attention per (b,c,h): 64 queries x 256 keys ----------
__global__ __launch_bounds__(256) void attn_kernel(
    const unsigned short* __restrict__ Q, const unsigned short* __restrict__ K,
    const unsigned short* __restrict__ V, unsigned short* __restrict__ O) {
  __shared__ alignas(16) unsigned short k_lds[256 * 64];
  __shared__ alignas(16) unsigned short v_t[64 * 256];
  // chunked XCD swizzle: all 16 heads of one (b,c) land on one XCD (KV L2 reuse)
  const int w = ((blockIdx.x & 7) << 9) | (blockIdx.x >> 3);
  const int h = w & 15;
  const int bc = w >> 4;
  const int tid = threadIdx.x;
  const int lane = tid & 63;
  const int wid = tid >> 6;
  const size_t kv0 = (size_t)bc * 256 * 1024 + h * 64;

  bf16x8 qf[2];
  {
    const size_t qrow = (size_t)bc * 64 + wid * 16 + (lane & 15);
    const unsigned short* qp = Q + qrow * 1024 + h * 64 + (lane >> 4) * 8;
    qf[0] = *(const bf16x8*)(qp);
    qf[1] = *(const bf16x8*)(qp + 32);
  }
#pragma unroll
  for (int it = 0; it < 8; ++it) {
    const int j = it * 32 + (tid >> 3);
    const int c = tid & 7;
    const uint4 kv = *(const uint4*)(K + kv0 + (size_t)j * 1024 + c * 8);
    *(uint4*)((char*)k_lds + j * 128 + ((c ^ (j & 7)) * 16)) = kv;
  }
  {
    const int j = (tid >> 1) * 2;
    const int half = tid & 1;
#pragma unroll
    for (int cc2 = 0; cc2 < 4; ++cc2) {
      const int chunk = half * 4 + cc2;
      const int d0 = chunk * 8;
      u16x8 a = *(const u16x8*)(V + kv0 + (size_t)j * 1024 + d0);
      u16x8 b = *(const u16x8*)(V + kv0 + (size_t)(j + 1) * 1024 + d0);
#pragma unroll
      for (int dd = 0; dd < 8; ++dd) {
        const int d = d0 + dd;
        unsigned int p = (unsigned int)a[dd] | ((unsigned int)b[dd] << 16);
        *(unsigned int*)((char*)v_t + d * 512 + (((j >> 3) ^ (d & 7)) * 16) + ((j & 7) * 2)) = p;
      }
    }
  }
  __syncthreads();

  f32x4 accs[16] = {};
#pragma unroll
  for (int jt = 0; jt < 16; ++jt) {
#pragma unroll
    for (int ks = 0; ks < 2; ++ks) {
      const int r = jt * 16 + (lane & 15);
      bf16x8 kf = *(const bf16x8*)((const char*)k_lds + r * 128 +
                                   (((ks * 4 + (lane >> 4)) ^ (r & 7)) * 16));
      accs[jt] = __builtin_amdgcn_mfma_f32_16x16x32_bf16(qf[ks], kf, accs[jt], 0, 0, 0);
    }
  }
  __syncthreads();

  float inv_[4];
#pragma unroll
  for (int r = 0; r < 4; ++r) {
    float m = accs[0][r];
#pragma unroll
    for (int jt = 1; jt < 16; ++jt) m = fmaxf(m, accs[jt][r]);
#pragma unroll
    for (int mk = 1; mk < 16; mk <<= 1) m = fmaxf(m, __shfl_xor(m, mk));
    float s = 0.f;
#pragma unroll
    for (int jt = 0; jt < 16; ++jt) {
      float p = __expf((accs[jt][r] - m) * 0.125f);
      accs[jt][r] = p;
      s += p;
    }
#pragma unroll
    for (int mk = 1; mk < 16; mk <<= 1) s += __shfl_xor(s, mk);
    inv_[r] = 1.0f / s;
  }
  char* pbase = (char*)k_lds + wid * 8192;
  {
    const int jc = lane & 15;
    const int i0 = (lane >> 4) * 4;
#pragma unroll
    for (int jt = 0; jt < 16; ++jt) {
      const int j = jt * 16 + jc;
#pragma unroll
      for (int r = 0; r < 4; ++r) {
        const int i = i0 + r;
        *(unsigned short*)(pbase + i * 512 + (((j >> 3) ^ (i & 7)) * 16) + ((j & 7) * 2)) =
            f2bf(accs[jt][r] * inv_[r]);
      }
    }
  }
  __syncthreads();

  f32x4 acco[4] = {};
#pragma unroll
  for (int jb = 0; jb < 8; ++jb) {
    const int i = lane & 15;
    bf16x8 pf = *(const bf16x8*)(pbase + i * 512 + (((jb * 4 + (lane >> 4)) ^ (i & 7)) * 16));
#pragma unroll
    for (int ni = 0; ni < 4; ++ni) {
      const int d = ni * 16 + (lane & 15);
      bf16x8 vf = *(const bf16x8*)((const char*)v_t + d * 512 +
                                   (((jb * 4 + (lane >> 4)) ^ (d & 7)) * 16));
      acco[ni] = __builtin_amdgcn_mfma_f32_16x16x32_bf16(pf, vf, acco[ni], 0, 0, 0);
    }
  }
  {
    const size_t row0 = (size_t)bc * 64 + wid * 16 + (lane >> 4) * 4;
#pragma unroll
    for (int ni = 0; ni < 4; ++ni) {
      const int col = h * 64 + ni * 16 + (lane & 15);
#pragma unroll
      for (int r = 0; r < 4; ++r) {
        O[(row0 + r) * 1024 + col] = f2bf(acco[ni][r]);
      }
    }
  }
}

extern "C" void kernel_launch(void* const* d_in, const int* in_sizes, int n_in,
                              void* d_out, int out_size, void* d_ws, size_t ws_size,
                              hipStream_t stream) {
  const float* h = (const float*)d_in[0];
  const float* e = (const float*)d_in[1];
  const float* Wq = (const float*)d_in[2];
  const float* bq = (const float*)d_in[3];
  const float* Wk = (const float*)d_in[4];
  const float* bk = (const float*)d_in[5];
  const float* Wv = (const float*)d_in[6];
  const float* bv = (const float*)d_in[7];
  const float* gamma = (const float*)d_in[8];
  const float* beta = (const float*)d_in[9];
  const float* Wo = (const float*)d_in[10];
  const float* bo = (const float*)d_in[11];
  float* out = (float*)d_out;

  char* ws = (char*)d_ws;
  unsigned short* x = (unsigned short*)ws;                        // 32MB (reused as o)
  unsigned short* q = (unsigned short*)(ws + (32ull << 20));      // 32MB
  unsigned short* kbuf = (unsigned short*)(ws + (64ull << 20));   // 128MB
  unsigned short* vbuf = (unsigned short*)(ws + (192ull << 20));  // 128MB
  unsigned short* ebf = (unsigned short*)(ws + (320ull << 20));   // 128MB
  unsigned short* wqT = (unsigned short*)(ws + (448ull << 20));   // 2MB
  unsigned short* wkvT = (unsigned short*)(ws + (450ull << 20));  // 4MB
  unsigned short* woT = (unsigned short*)(ws + (454ull << 20));   // 2MB
  unsigned short* o = x;

  dim3 tb(256);
  cvt_bf16<<<2048, tb, 0, stream>>>(e, ebf, 8388608L);
  transpose_w<<<dim3(16, 16), tb, 0, stream>>>(Wq, wqT);
  transpose_w<<<dim3(16, 16), tb, 0, stream>>>(Wk, wkvT);
  transpose_w<<<dim3(16, 16), tb, 0, stream>>>(Wv, wkvT + 1024 * 1024);
  transpose_w<<<dim3(16, 16), tb, 0, stream>>>(Wo, woT);
  ln_kernel<<<16384, tb, 0, stream>>>(h, gamma, beta, x);
  // Q = x @ Wq + bq
  gemm256<0><<<dim3(4, 64), dim3(512), 0, stream>>>(x, wqT, bq, nullptr, q, nullptr,
                                                    nullptr, nullptr);
  // [K|V] = e @ [Wk|Wv] + [bk|bv]
  gemm256<0><<<dim3(8, 256), dim3(512), 0, stream>>>(ebf, wkvT, bk, bv, kbuf, vbuf,
                                                     nullptr, nullptr);
  // attention
  attn_kernel<<<4096, tb, 0, stream>>>(q, kbuf, vbuf, o);
  // rows t<63: out = h
  fill_head<<<504, tb, 0, stream>>>(h, out);
  // rows t>=63: out = h + shift63(o @ Wo + bo)
  gemm256<1><<<dim3(4, 64), dim3(512), 0, stream>>>(o, woT, bo, nullptr, nullptr, nullptr,
                                                    h, out);
}